// Round 8
// baseline (405.385 us; speedup 1.0000x reference)
//
#include <hip/hip_runtime.h>
#include <hip/hip_fp16.h>

#define DD 64
#define NUM_GRAPHS 64
#define CAP 48          // bucket capacity per node (Poisson deg ~16; overflow list covers rest)
#define OVF_CAP 16384
#define AGG_BLOCKS 2048

// ---- fused ticket + bucket fill: one atomic pass builds the grouped-by-dst edge list ----
__global__ void k_ticket_fill(const int* __restrict__ row, const int* __restrict__ col,
                              int* __restrict__ cnt, int* __restrict__ bsrc,
                              int2* __restrict__ ovf, int* __restrict__ ovf_cnt, int E) {
    int e = blockIdx.x * blockDim.x + threadIdx.x;
    if (e >= E) return;
    int c = col[e], r = row[e];
    int t = atomicAdd(&cnt[c], 1);
    if (t < CAP) {
        bsrc[c * CAP + t] = r;
    } else {
        int i = atomicAdd(ovf_cnt, 1);
        if (i < OVF_CAP) ovf[i] = make_int2(c, r);
    }
}

// ---- dinv + packed per-node {node_type, dinv} ----
__global__ void k_dinv_pack(const int* __restrict__ cnt, const int* __restrict__ nt,
                            float* __restrict__ dinv, int2* __restrict__ pk, int N) {
    int i = blockIdx.x * blockDim.x + threadIdx.x;
    if (i >= N) return;
    float di = rsqrtf((float)cnt[i] + 1.0f);   // +1 = self loop
    dinv[i] = di;
    pk[i] = make_int2(nt[i], __float_as_int(di));
}

// ---- per-edge packed operand in bucket order: epku = (nt[src]<<16) | half(dinv[src]) ----
__global__ void k_buildepk(const int* __restrict__ bsrc, const int* __restrict__ cnt,
                           const int2* __restrict__ pk, unsigned* __restrict__ epku, int N) {
    int s = blockIdx.x * blockDim.x + threadIdx.x;
    if (s >= N * CAP) return;
    int node = s / CAP;
    int t = s - node * CAP;
    int deg = cnt[node]; if (deg > CAP) deg = CAP;
    if (t >= deg) return;
    int2 p = pk[bsrc[s]];
    float d = __int_as_float(p.y);
    epku[s] = ((unsigned)p.x << 16) | (unsigned)__half_as_ushort(__float2half(d));
}

// ---- embW1 = emb_table @ W1  (30 x 64, tiny) ----
__global__ void k_embW1(const float* __restrict__ emb, const float* __restrict__ W1,
                        float* __restrict__ embW1, int V) {
    __shared__ float er[DD];
    int v = blockIdx.x, j = threadIdx.x;
    er[j] = emb[v * DD + j];
    __syncthreads();
    float acc = 0.0f;
    #pragma unroll
    for (int d = 0; d < DD; ++d) acc += er[d] * W1[d * DD + j];
    embW1[v * DD + j] = acc;
}

// per-wave row @ W with W column cached in VGPRs (Wcol[d] = W[d][j])
__device__ __forceinline__ float rowmatmul(float v, const float* Wcol) {
    int vb = __float_as_int(v);
    float o0 = 0.f, o1 = 0.f, o2 = 0.f, o3 = 0.f;
    #pragma unroll
    for (int d = 0; d < DD; d += 4) {
        o0 = fmaf(__int_as_float(__builtin_amdgcn_readlane(vb, d + 0)), Wcol[d + 0], o0);
        o1 = fmaf(__int_as_float(__builtin_amdgcn_readlane(vb, d + 1)), Wcol[d + 1], o1);
        o2 = fmaf(__int_as_float(__builtin_amdgcn_readlane(vb, d + 2)), Wcol[d + 2], o2);
        o3 = fmaf(__int_as_float(__builtin_amdgcn_readlane(vb, d + 3)), Wcol[d + 3], o3);
    }
    return (o0 + o1) + (o2 + o3);
}

// split-wave half2 gather-sum, 8-edge unrolled (4 loads in flight per half-wave).
__device__ __forceinline__ float2 gather_sum_h2(const int* __restrict__ srcidx,
                                                const __half* __restrict__ Hs,
                                                int s, int e, int half_id, int p) {
    float ax = 0.f, ay = 0.f, bx = 0.f, by = 0.f;
    float cx = 0.f, cy = 0.f, dx = 0.f, dy = 0.f;
    int k = s, rem = e - s;
    if (rem & 1) {
        if (!half_id) {
            float2 f = __half22float2(*(const __half2*)(Hs + (long)srcidx[k] * DD + 2 * p));
            ax += f.x; ay += f.y;
        }
        k += 1;
    }
    if (rem & 2) {
        int sel = srcidx[k + half_id];
        float2 f = __half22float2(*(const __half2*)(Hs + (long)sel * DD + 2 * p));
        ax += f.x; ay += f.y;
        k += 2;
    }
    if (rem & 4) {
        int sA = srcidx[k + half_id];
        int sB = srcidx[k + 2 + half_id];
        float2 fA = __half22float2(*(const __half2*)(Hs + (long)sA * DD + 2 * p));
        float2 fB = __half22float2(*(const __half2*)(Hs + (long)sB * DD + 2 * p));
        ax += fA.x; ay += fA.y; bx += fB.x; by += fB.y;
        k += 4;
    }
    for (; k < e; k += 8) {
        int sA = srcidx[k + half_id];
        int sB = srcidx[k + 2 + half_id];
        int sC = srcidx[k + 4 + half_id];
        int sD = srcidx[k + 6 + half_id];
        float2 fA = __half22float2(*(const __half2*)(Hs + (long)sA * DD + 2 * p));
        float2 fB = __half22float2(*(const __half2*)(Hs + (long)sB * DD + 2 * p));
        float2 fC = __half22float2(*(const __half2*)(Hs + (long)sC * DD + 2 * p));
        float2 fD = __half22float2(*(const __half2*)(Hs + (long)sD * DD + 2 * p));
        ax += fA.x; ay += fA.y; bx += fB.x; by += fB.y;
        cx += fC.x; cy += fC.y; dx += fD.x; dy += fD.y;
    }
    ax += bx + cx + dx; ay += by + cy + dy;
    ax += __shfl_xor(ax, 32, 64);
    ay += __shfl_xor(ay, 32, 64);
    return make_float2(ax, ay);
}

// ---- layer-1 fused: v = relu((Σ ew[t_e]*d_e + ew[nt[c]]*dc)*dc + b1);
//      OUT[c] = fp16( (v @ W2) * dc ) ----
__global__ __launch_bounds__(256) void k_agg1_fused(const int* __restrict__ cnt,
                                                    const unsigned* __restrict__ epku,
                                                    const int2* __restrict__ pk,
                                                    const float* __restrict__ embW1,
                                                    const float* __restrict__ b1,
                                                    const float* __restrict__ W2,
                                                    const int2* __restrict__ ovf,
                                                    const int* __restrict__ ovf_cnt,
                                                    __half* __restrict__ OUT, int N, int V) {
    __shared__ float ew[30 * DD];
    int tid = threadIdx.x;
    for (int k = tid; k < V * DD; k += 256) ew[k] = embW1[k];
    __syncthreads();
    int j = tid & 63;
    float Wcol[DD];
    #pragma unroll
    for (int d = 0; d < DD; ++d) Wcol[d] = W2[d * DD + j];
    float bj = b1[j];
    int M = min(*ovf_cnt, OVF_CAP);
    int wave0 = blockIdx.x * 4 + (tid >> 6);
    int wstride = gridDim.x * 4;
    for (int node = __builtin_amdgcn_readfirstlane(wave0); node < N;
         node += wstride) {
        int deg = cnt[node]; if (deg > CAP) deg = CAP;
        int s = node * CAP, e = s + deg;
        float acc = 0.0f;
        int k = s;
        for (; k + 7 < e; k += 8) {
            unsigned u0 = epku[k],   u1 = epku[k+1], u2 = epku[k+2], u3 = epku[k+3];
            unsigned u4 = epku[k+4], u5 = epku[k+5], u6 = epku[k+6], u7 = epku[k+7];
            acc += ew[(u0 >> 16) * DD + j] * __half2float(__ushort_as_half((unsigned short)(u0 & 0xFFFF)))
                 + ew[(u1 >> 16) * DD + j] * __half2float(__ushort_as_half((unsigned short)(u1 & 0xFFFF)))
                 + ew[(u2 >> 16) * DD + j] * __half2float(__ushort_as_half((unsigned short)(u2 & 0xFFFF)))
                 + ew[(u3 >> 16) * DD + j] * __half2float(__ushort_as_half((unsigned short)(u3 & 0xFFFF)));
            acc += ew[(u4 >> 16) * DD + j] * __half2float(__ushort_as_half((unsigned short)(u4 & 0xFFFF)))
                 + ew[(u5 >> 16) * DD + j] * __half2float(__ushort_as_half((unsigned short)(u5 & 0xFFFF)))
                 + ew[(u6 >> 16) * DD + j] * __half2float(__ushort_as_half((unsigned short)(u6 & 0xFFFF)))
                 + ew[(u7 >> 16) * DD + j] * __half2float(__ushort_as_half((unsigned short)(u7 & 0xFFFF)));
        }
        for (; k < e; ++k) {
            unsigned u0 = epku[k];
            acc += ew[(u0 >> 16) * DD + j] * __half2float(__ushort_as_half((unsigned short)(u0 & 0xFFFF)));
        }
        for (int m = 0; m < M; ++m) {
            int2 o = ovf[m];
            if (o.x == node) {
                int2 ps = pk[o.y];
                acc += ew[ps.x * DD + j] * __int_as_float(ps.y);
            }
        }
        int2 pc = pk[node];
        float dc = __int_as_float(pc.y);
        float v = (acc + ew[pc.x * DD + j] * dc) * dc + bj;
        v = fmaxf(v, 0.0f);
        OUT[(long)node * DD + j] = __float2half(rowmatmul(v, Wcol) * dc);
    }
}

// ---- layer-2: split-wave half2 gather; v=relu((Σ+self)*dc+b2); OUT=fp16((v@W3)*dc) ----
__global__ __launch_bounds__(256) void k_agg2_fused(const int* __restrict__ cnt,
                                                    const int* __restrict__ bsrc,
                                                    const float* __restrict__ dinv,
                                                    const __half* __restrict__ Hs,
                                                    const float* __restrict__ b2,
                                                    const float* __restrict__ W3,
                                                    const int2* __restrict__ ovf,
                                                    const int* __restrict__ ovf_cnt,
                                                    __half* __restrict__ OUT, int N) {
    int tid = threadIdx.x;
    int lane = tid & 63;
    int half_id = lane >> 5, p = lane & 31;
    float Wcol[DD];
    #pragma unroll
    for (int d = 0; d < DD; ++d) Wcol[d] = W3[d * DD + lane];
    float2 b2p = *(const float2*)(b2 + 2 * p);
    int M = min(*ovf_cnt, OVF_CAP);
    int wave0 = blockIdx.x * 4 + (tid >> 6);
    int wstride = gridDim.x * 4;
    for (int node = __builtin_amdgcn_readfirstlane(wave0); node < N;
         node += wstride) {
        int deg = cnt[node]; if (deg > CAP) deg = CAP;
        int s = node * CAP, e = s + deg;
        float2 acc = gather_sum_h2(bsrc, Hs, s, e, half_id, p);
        for (int m = 0; m < M; ++m) {
            int2 o = ovf[m];
            if (o.x == node) {
                float2 f = __half22float2(*(const __half2*)(Hs + (long)o.y * DD + 2 * p));
                acc.x += f.x; acc.y += f.y;
            }
        }
        float dc = dinv[node];
        float2 self = __half22float2(*(const __half2*)(Hs + (long)node * DD + 2 * p));
        float vx = fmaxf((acc.x + self.x) * dc + b2p.x, 0.f);
        float vy = fmaxf((acc.y + self.y) * dc + b2p.y, 0.f);
        int vxb = __float_as_int(vx), vyb = __float_as_int(vy);
        float o0 = 0.f, o1 = 0.f, o2 = 0.f, o3 = 0.f;
        #pragma unroll
        for (int d = 0; d < DD; d += 4) {
            o0 = fmaf(__int_as_float(__builtin_amdgcn_readlane(vxb, d >> 1)), Wcol[d + 0], o0);
            o1 = fmaf(__int_as_float(__builtin_amdgcn_readlane(vyb, d >> 1)), Wcol[d + 1], o1);
            o2 = fmaf(__int_as_float(__builtin_amdgcn_readlane(vxb, (d >> 1) + 1)), Wcol[d + 2], o2);
            o3 = fmaf(__int_as_float(__builtin_amdgcn_readlane(vyb, (d >> 1) + 1)), Wcol[d + 3], o3);
        }
        float o = (o0 + o1) + (o2 + o3);
        OUT[(long)node * DD + lane] = __float2half(o * dc);
    }
}

// ---- layer-3 fused with pooling: contiguous node chunks per wave (batch sorted) ----
__global__ __launch_bounds__(256) void k_agg3_pool(const int* __restrict__ cnt,
                                                   const int* __restrict__ bsrc,
                                                   const float* __restrict__ dinv,
                                                   const __half* __restrict__ Hs,
                                                   const float* __restrict__ b3,
                                                   const int* __restrict__ batch,
                                                   const int2* __restrict__ ovf,
                                                   const int* __restrict__ ovf_cnt,
                                                   float* __restrict__ pool,
                                                   int N, int chunk) {
    int tid = threadIdx.x;
    int lane = tid & 63;
    int half_id = lane >> 5, p = lane & 31;
    int w = __builtin_amdgcn_readfirstlane(blockIdx.x * 4 + (tid >> 6));
    int start = w * chunk;
    if (start >= N) return;
    int endn = min(N, start + chunk);
    float2 b3p = *(const float2*)(b3 + 2 * p);
    int M = min(*ovf_cnt, OVF_CAP);
    int gcur = batch[start];
    float2 pacc = make_float2(0.f, 0.f);
    for (int node = start; node < endn; ++node) {
        int deg = cnt[node]; if (deg > CAP) deg = CAP;
        int s = node * CAP, e = s + deg;
        float2 acc = gather_sum_h2(bsrc, Hs, s, e, half_id, p);
        for (int m = 0; m < M; ++m) {
            int2 o = ovf[m];
            if (o.x == node) {
                float2 f = __half22float2(*(const __half2*)(Hs + (long)o.y * DD + 2 * p));
                acc.x += f.x; acc.y += f.y;
            }
        }
        float dc = dinv[node];
        float2 self = __half22float2(*(const __half2*)(Hs + (long)node * DD + 2 * p));
        float vx = (acc.x + self.x) * dc + b3p.x;
        float vy = (acc.y + self.y) * dc + b3p.y;
        int g = batch[node];
        if (g != gcur) {
            if (!half_id) {
                atomicAdd(&pool[gcur * DD + 2 * p],     pacc.x);
                atomicAdd(&pool[gcur * DD + 2 * p + 1], pacc.y);
            }
            gcur = g;
            pacc = make_float2(vx, vy);
        } else {
            pacc.x += vx; pacc.y += vy;
        }
    }
    if (!half_id) {
        atomicAdd(&pool[gcur * DD + 2 * p],     pacc.x);
        atomicAdd(&pool[gcur * DD + 2 * p + 1], pacc.y);
    }
}

// ---- final: mean + L2 normalize ----
__global__ void k_final(const float* __restrict__ pool, const int* __restrict__ batch,
                        float* __restrict__ out, int N) {
    int g = blockIdx.x, j = threadIdx.x;
    int lo = 0, hi = N;
    while (lo < hi) { int m = (lo + hi) >> 1; if (batch[m] < g) lo = m + 1; else hi = m; }
    int lo2 = lo; hi = N;
    while (lo2 < hi) { int m = (lo2 + hi) >> 1; if (batch[m] < g + 1) lo2 = m + 1; else hi = m; }
    float cnt = fmaxf((float)(lo2 - lo), 1.0f);
    float v = pool[g * DD + j] / cnt;
    float sq = v * v;
    #pragma unroll
    for (int off = 32; off > 0; off >>= 1) sq += __shfl_down(sq, off, 64);
    float nrm = __shfl(sq, 0, 64);
    out[g * DD + j] = v / sqrtf(nrm);
}

extern "C" void kernel_launch(void* const* d_in, const int* in_sizes, int n_in,
                              void* d_out, int out_size, void* d_ws, size_t ws_size,
                              hipStream_t stream) {
    const int*   node_types = (const int*)d_in[0];
    const int*   edge_index = (const int*)d_in[1];
    const int*   batch      = (const int*)d_in[2];
    const float* emb        = (const float*)d_in[3];
    const float* W1 = (const float*)d_in[4];
    const float* b1 = (const float*)d_in[5];
    const float* W2 = (const float*)d_in[6];
    const float* b2 = (const float*)d_in[7];
    const float* W3 = (const float*)d_in[8];
    const float* b3 = (const float*)d_in[9];
    const int N = in_sizes[0];
    const int E = in_sizes[1] / 2;
    const int V = in_sizes[3] / DD;
    const int* row = edge_index;
    const int* col = edge_index + E;
    const long ND = (long)N * DD;

    // workspace layout (~66 MB)
    char* p = (char*)d_ws;
    __half*   hsA  = (__half*)p;          p += ND * sizeof(__half);
    __half*   hsB  = (__half*)p;          p += ND * sizeof(__half);
    int*      bsrc = (int*)p;             p += (size_t)N * CAP * sizeof(int);
    unsigned* epku = (unsigned*)p;        p += (size_t)N * CAP * sizeof(unsigned);
    float*    dinv = (float*)p;           p += (size_t)N * sizeof(float);
    int2*     pk   = (int2*)p;            p += (size_t)N * sizeof(int2);
    int*      cnt  = (int*)p;             p += (size_t)(N + 4) * sizeof(int);
    int2*     ovf  = (int2*)p;            p += (size_t)OVF_CAP * sizeof(int2);
    float*    pool = (float*)p;           p += (size_t)NUM_GRAPHS * DD * sizeof(float);
    float*    embW1= (float*)p;           p += (size_t)V * DD * sizeof(float);
    int* ovf_cnt = cnt + N;

    // ---- bucket CSR build: ONE atomic pass ----
    hipMemsetAsync(cnt, 0, (size_t)(N + 1) * sizeof(int), stream);
    k_ticket_fill<<<(E + 255) / 256, 256, 0, stream>>>(row, col, cnt, bsrc, ovf, ovf_cnt, E);
    k_dinv_pack<<<(N + 255) / 256, 256, 0, stream>>>(cnt, node_types, dinv, pk, N);
    k_buildepk<<<(N * CAP + 255) / 256, 256, 0, stream>>>(bsrc, cnt, pk, epku, N);

    // ---- layer 1 fused with @W2*dinv -> fp16 ----
    k_embW1<<<V, DD, 0, stream>>>(emb, W1, embW1, V);
    k_agg1_fused<<<AGG_BLOCKS, 256, 0, stream>>>(cnt, epku, pk, embW1, b1, W2,
                                                 ovf, ovf_cnt, hsA, N, V);
    // ---- layer 2 fused with @W3*dinv -> fp16 ----
    k_agg2_fused<<<AGG_BLOCKS, 256, 0, stream>>>(cnt, bsrc, dinv, hsA, b2, W3,
                                                 ovf, ovf_cnt, hsB, N);
    // ---- layer 3 fused with pooling ----
    hipMemsetAsync(pool, 0, (size_t)(NUM_GRAPHS * DD) * sizeof(float), stream);
    const int totalWaves = AGG_BLOCKS * 4;
    const int chunk = (N + totalWaves - 1) / totalWaves;
    k_agg3_pool<<<AGG_BLOCKS, 256, 0, stream>>>(cnt, bsrc, dinv, hsB, b3, batch,
                                                ovf, ovf_cnt, pool, N, chunk);
    // ---- normalize ----
    k_final<<<NUM_GRAPHS, DD, 0, stream>>>(pool, batch, (float*)d_out, N);
}

// Round 9
// 312.203 us; speedup vs baseline: 1.2985x; 1.2985x over previous
//
#include <hip/hip_runtime.h>
#include <hip/hip_fp16.h>

#define DD 64
#define NUM_GRAPHS 64
#define AGG_BLOCKS 2048
#define EB 512          // edge-blocks for hist/scatter passes
#define BINW 256        // nodes per bin
#define MAXNB 512       // LDS capacity for bin counters
#define EBIN_CAP 6144   // max edges per bin staged in LDS (mean 4096, sd 64)

// ---- pass A: per-edge-block histogram over bins (LDS atomics only) ----
__global__ __launch_bounds__(256) void k_hist(const int* __restrict__ col,
                                              int* __restrict__ H, int E, int NB, int CE) {
    __shared__ int h[MAXNB];
    int eb = blockIdx.x, t = threadIdx.x;
    for (int i = t; i < NB; i += 256) h[i] = 0;
    __syncthreads();
    int e0 = eb * CE, e1 = min(E, e0 + CE);
    for (int e = e0 + t; e < e1; e += 256) atomicAdd(&h[col[e] >> 8], 1);
    __syncthreads();
    for (int i = t; i < NB; i += 256) H[eb * NB + i] = h[i];
}

// ---- pass B1: for each bin, exclusive scan over the EB edge-blocks; bintot out ----
__global__ __launch_bounds__(256) void k_scanA(int* __restrict__ H,
                                               int* __restrict__ bintot, int NB) {
    __shared__ int s[256];
    int b = blockIdx.x, t = threadIdx.x;
    int i0 = (2 * t) * NB + b, i1 = (2 * t + 1) * NB + b;
    int v0 = H[i0], v1 = H[i1];
    int tot = v0 + v1;
    s[t] = tot;
    __syncthreads();
    for (int off = 1; off < 256; off <<= 1) {
        int tv = (t >= off) ? s[t - off] : 0;
        __syncthreads();
        s[t] += tv;
        __syncthreads();
    }
    int excl = s[t] - tot;
    H[i0] = excl;
    H[i1] = excl + v0;
    if (t == 255) bintot[b] = s[255];
}

// ---- pass B2: exclusive scan of bin totals -> binstart[0..NB] ----
__global__ void k_scanB(const int* __restrict__ bintot, int* __restrict__ binstart, int NB) {
    __shared__ int s[512];
    int t = threadIdx.x;
    int v = (t < NB) ? bintot[t] : 0;
    s[t] = v;
    __syncthreads();
    for (int off = 1; off < 512; off <<= 1) {
        int tv = (t >= off) ? s[t - off] : 0;
        __syncthreads();
        s[t] += tv;
        __syncthreads();
    }
    if (t < NB) binstart[t] = s[t] - v;
    if (t == 511) binstart[NB] = s[511];
}

// ---- pass C: scatter packed edges into bin-contiguous regions (LDS cursors) ----
__global__ __launch_bounds__(256) void k_scatbin(const int* __restrict__ row,
                                                 const int* __restrict__ col,
                                                 const int* __restrict__ H,
                                                 const int* __restrict__ binstart,
                                                 unsigned* __restrict__ binned,
                                                 int E, int NB, int CE) {
    __shared__ int off[MAXNB];
    int eb = blockIdx.x, t = threadIdx.x;
    for (int i = t; i < NB; i += 256) off[i] = binstart[i] + H[eb * NB + i];
    __syncthreads();
    int e0 = eb * CE, e1 = min(E, e0 + CE);
    for (int e = e0 + t; e < e1; e += 256) {
        int c = col[e], r = row[e];
        int slot = atomicAdd(&off[c >> 8], 1);
        binned[slot] = ((unsigned)(c & 255) << 24) | (unsigned)r;
    }
}

// ---- pass D: per-bin CSR finalize entirely in LDS; dense srcidx/rowptr + dinv/pk ----
__global__ __launch_bounds__(256) void k_bincsr(const unsigned* __restrict__ binned,
                                                const int* __restrict__ binstart,
                                                const int* __restrict__ nt,
                                                int* __restrict__ srcidx,
                                                int* __restrict__ rowptr,
                                                float* __restrict__ dinv,
                                                int2* __restrict__ pk, int N, int NB) {
    __shared__ unsigned arr[EBIN_CAP];
    __shared__ int sorted_[EBIN_CAP];
    __shared__ int cnt[BINW];
    __shared__ int base[BINW];
    __shared__ int cursor[BINW];
    int b = blockIdx.x, t = threadIdx.x;
    int s0 = binstart[b], s1 = binstart[b + 1];
    int binsz = s1 - s0;
    if (binsz > EBIN_CAP) binsz = EBIN_CAP;   // statistically impossible; guards LDS
    cnt[t] = 0;
    for (int i = t; i < binsz; i += 256) arr[i] = binned[s0 + i];
    __syncthreads();
    for (int i = t; i < binsz; i += 256) atomicAdd(&cnt[arr[i] >> 24], 1);
    __syncthreads();
    int v = cnt[t];
    base[t] = v;
    __syncthreads();
    for (int off = 1; off < 256; off <<= 1) {
        int tv = (t >= off) ? base[t - off] : 0;
        __syncthreads();
        base[t] += tv;
        __syncthreads();
    }
    int excl = base[t] - v;
    __syncthreads();
    base[t] = excl;
    cursor[t] = excl;
    __syncthreads();
    for (int i = t; i < binsz; i += 256) {
        unsigned val = arr[i];
        int pos = atomicAdd(&cursor[val >> 24], 1);
        sorted_[pos] = (int)(val & 0xFFFFFF);
    }
    __syncthreads();
    for (int i = t; i < binsz; i += 256) srcidx[s0 + i] = sorted_[i];
    int node = b * BINW + t;
    if (node < N) {
        rowptr[node] = s0 + base[t];
        float di = rsqrtf((float)cnt[t] + 1.0f);   // +1 = self loop
        dinv[node] = di;
        pk[node] = make_int2(nt[node], __float_as_int(di));
    }
    if (b == NB - 1 && t == 0) rowptr[N] = s1;
}

// ---- per-edge packed operand in CSR order: epku = (nt[src]<<16) | half(dinv[src]) ----
__global__ void k_buildepk(const int* __restrict__ srcidx, const int2* __restrict__ pk,
                           unsigned* __restrict__ epku, int E) {
    int i = blockIdx.x * blockDim.x + threadIdx.x;
    if (i >= E) return;
    int2 p = pk[srcidx[i]];
    epku[i] = ((unsigned)p.x << 16) |
              (unsigned)__half_as_ushort(__float2half(__int_as_float(p.y)));
}

// ---- embW1 = emb_table @ W1  (30 x 64, tiny) ----
__global__ void k_embW1(const float* __restrict__ emb, const float* __restrict__ W1,
                        float* __restrict__ embW1, int V) {
    __shared__ float er[DD];
    int v = blockIdx.x, j = threadIdx.x;
    er[j] = emb[v * DD + j];
    __syncthreads();
    float acc = 0.0f;
    #pragma unroll
    for (int d = 0; d < DD; ++d) acc += er[d] * W1[d * DD + j];
    embW1[v * DD + j] = acc;
}

// per-wave row @ W with W column cached in VGPRs (Wcol[d] = W[d][j])
__device__ __forceinline__ float rowmatmul(float v, const float* Wcol) {
    int vb = __float_as_int(v);
    float o0 = 0.f, o1 = 0.f, o2 = 0.f, o3 = 0.f;
    #pragma unroll
    for (int d = 0; d < DD; d += 4) {
        o0 = fmaf(__int_as_float(__builtin_amdgcn_readlane(vb, d + 0)), Wcol[d + 0], o0);
        o1 = fmaf(__int_as_float(__builtin_amdgcn_readlane(vb, d + 1)), Wcol[d + 1], o1);
        o2 = fmaf(__int_as_float(__builtin_amdgcn_readlane(vb, d + 2)), Wcol[d + 2], o2);
        o3 = fmaf(__int_as_float(__builtin_amdgcn_readlane(vb, d + 3)), Wcol[d + 3], o3);
    }
    return (o0 + o1) + (o2 + o3);
}

// split-wave half2 gather-sum, 8-edge unrolled (4 loads in flight per half-wave).
__device__ __forceinline__ float2 gather_sum_h2(const int* __restrict__ srcidx,
                                                const __half* __restrict__ Hs,
                                                int s, int e, int half_id, int p) {
    float ax = 0.f, ay = 0.f, bx = 0.f, by = 0.f;
    float cx = 0.f, cy = 0.f, dx = 0.f, dy = 0.f;
    int k = s, rem = e - s;
    if (rem & 1) {
        if (!half_id) {
            float2 f = __half22float2(*(const __half2*)(Hs + (long)srcidx[k] * DD + 2 * p));
            ax += f.x; ay += f.y;
        }
        k += 1;
    }
    if (rem & 2) {
        int sel = srcidx[k + half_id];
        float2 f = __half22float2(*(const __half2*)(Hs + (long)sel * DD + 2 * p));
        ax += f.x; ay += f.y;
        k += 2;
    }
    if (rem & 4) {
        int sA = srcidx[k + half_id];
        int sB = srcidx[k + 2 + half_id];
        float2 fA = __half22float2(*(const __half2*)(Hs + (long)sA * DD + 2 * p));
        float2 fB = __half22float2(*(const __half2*)(Hs + (long)sB * DD + 2 * p));
        ax += fA.x; ay += fA.y; bx += fB.x; by += fB.y;
        k += 4;
    }
    for (; k < e; k += 8) {
        int sA = srcidx[k + half_id];
        int sB = srcidx[k + 2 + half_id];
        int sC = srcidx[k + 4 + half_id];
        int sD = srcidx[k + 6 + half_id];
        float2 fA = __half22float2(*(const __half2*)(Hs + (long)sA * DD + 2 * p));
        float2 fB = __half22float2(*(const __half2*)(Hs + (long)sB * DD + 2 * p));
        float2 fC = __half22float2(*(const __half2*)(Hs + (long)sC * DD + 2 * p));
        float2 fD = __half22float2(*(const __half2*)(Hs + (long)sD * DD + 2 * p));
        ax += fA.x; ay += fA.y; bx += fB.x; by += fB.y;
        cx += fC.x; cy += fC.y; dx += fD.x; dy += fD.y;
    }
    ax += bx + cx + dx; ay += by + cy + dy;
    ax += __shfl_xor(ax, 32, 64);
    ay += __shfl_xor(ay, 32, 64);
    return make_float2(ax, ay);
}

// ---- layer-1 fused: v = relu((Σ ew[t_e]*d_e + ew[nt[c]]*dc)*dc + b1);
//      OUT[c] = fp16( (v @ W2) * dc ) ----
__global__ __launch_bounds__(256) void k_agg1_fused(const int* __restrict__ rowptr,
                                                    const unsigned* __restrict__ epku,
                                                    const int2* __restrict__ pk,
                                                    const float* __restrict__ embW1,
                                                    const float* __restrict__ b1,
                                                    const float* __restrict__ W2,
                                                    __half* __restrict__ OUT, int N, int V) {
    __shared__ float ew[30 * DD];
    int tid = threadIdx.x;
    for (int k = tid; k < V * DD; k += 256) ew[k] = embW1[k];
    __syncthreads();
    int j = tid & 63;
    float Wcol[DD];
    #pragma unroll
    for (int d = 0; d < DD; ++d) Wcol[d] = W2[d * DD + j];
    float bj = b1[j];
    int wave0 = blockIdx.x * 4 + (tid >> 6);
    int wstride = gridDim.x * 4;
    for (int node = __builtin_amdgcn_readfirstlane(wave0); node < N;
         node += wstride) {
        int s = rowptr[node], e = rowptr[node + 1];
        float acc = 0.0f;
        int k = s;
        for (; k + 7 < e; k += 8) {
            unsigned u0 = epku[k],   u1 = epku[k+1], u2 = epku[k+2], u3 = epku[k+3];
            unsigned u4 = epku[k+4], u5 = epku[k+5], u6 = epku[k+6], u7 = epku[k+7];
            acc += ew[(u0 >> 16) * DD + j] * __half2float(__ushort_as_half((unsigned short)(u0 & 0xFFFF)))
                 + ew[(u1 >> 16) * DD + j] * __half2float(__ushort_as_half((unsigned short)(u1 & 0xFFFF)))
                 + ew[(u2 >> 16) * DD + j] * __half2float(__ushort_as_half((unsigned short)(u2 & 0xFFFF)))
                 + ew[(u3 >> 16) * DD + j] * __half2float(__ushort_as_half((unsigned short)(u3 & 0xFFFF)));
            acc += ew[(u4 >> 16) * DD + j] * __half2float(__ushort_as_half((unsigned short)(u4 & 0xFFFF)))
                 + ew[(u5 >> 16) * DD + j] * __half2float(__ushort_as_half((unsigned short)(u5 & 0xFFFF)))
                 + ew[(u6 >> 16) * DD + j] * __half2float(__ushort_as_half((unsigned short)(u6 & 0xFFFF)))
                 + ew[(u7 >> 16) * DD + j] * __half2float(__ushort_as_half((unsigned short)(u7 & 0xFFFF)));
        }
        for (; k < e; ++k) {
            unsigned u0 = epku[k];
            acc += ew[(u0 >> 16) * DD + j] * __half2float(__ushort_as_half((unsigned short)(u0 & 0xFFFF)));
        }
        int2 pc = pk[node];
        float dc = __int_as_float(pc.y);
        float v = (acc + ew[pc.x * DD + j] * dc) * dc + bj;
        v = fmaxf(v, 0.0f);
        OUT[(long)node * DD + j] = __float2half(rowmatmul(v, Wcol) * dc);
    }
}

// ---- layer-2: split-wave half2 gather; v=relu((Σ+self)*dc+b2); OUT=fp16((v@W3)*dc) ----
__global__ __launch_bounds__(256) void k_agg2_fused(const int* __restrict__ rowptr,
                                                    const int* __restrict__ srcidx,
                                                    const float* __restrict__ dinv,
                                                    const __half* __restrict__ Hs,
                                                    const float* __restrict__ b2,
                                                    const float* __restrict__ W3,
                                                    __half* __restrict__ OUT, int N) {
    int tid = threadIdx.x;
    int lane = tid & 63;
    int half_id = lane >> 5, p = lane & 31;
    float Wcol[DD];
    #pragma unroll
    for (int d = 0; d < DD; ++d) Wcol[d] = W3[d * DD + lane];
    float2 b2p = *(const float2*)(b2 + 2 * p);
    int wave0 = blockIdx.x * 4 + (tid >> 6);
    int wstride = gridDim.x * 4;
    for (int node = __builtin_amdgcn_readfirstlane(wave0); node < N;
         node += wstride) {
        int s = rowptr[node], e = rowptr[node + 1];
        float2 acc = gather_sum_h2(srcidx, Hs, s, e, half_id, p);
        float dc = dinv[node];
        float2 self = __half22float2(*(const __half2*)(Hs + (long)node * DD + 2 * p));
        float vx = fmaxf((acc.x + self.x) * dc + b2p.x, 0.f);
        float vy = fmaxf((acc.y + self.y) * dc + b2p.y, 0.f);
        int vxb = __float_as_int(vx), vyb = __float_as_int(vy);
        float o0 = 0.f, o1 = 0.f, o2 = 0.f, o3 = 0.f;
        #pragma unroll
        for (int d = 0; d < DD; d += 4) {
            o0 = fmaf(__int_as_float(__builtin_amdgcn_readlane(vxb, d >> 1)), Wcol[d + 0], o0);
            o1 = fmaf(__int_as_float(__builtin_amdgcn_readlane(vyb, d >> 1)), Wcol[d + 1], o1);
            o2 = fmaf(__int_as_float(__builtin_amdgcn_readlane(vxb, (d >> 1) + 1)), Wcol[d + 2], o2);
            o3 = fmaf(__int_as_float(__builtin_amdgcn_readlane(vyb, (d >> 1) + 1)), Wcol[d + 3], o3);
        }
        float o = (o0 + o1) + (o2 + o3);
        OUT[(long)node * DD + lane] = __float2half(o * dc);
    }
}

// ---- layer-3 fused with pooling: contiguous node chunks per wave (batch sorted) ----
__global__ __launch_bounds__(256) void k_agg3_pool(const int* __restrict__ rowptr,
                                                   const int* __restrict__ srcidx,
                                                   const float* __restrict__ dinv,
                                                   const __half* __restrict__ Hs,
                                                   const float* __restrict__ b3,
                                                   const int* __restrict__ batch,
                                                   float* __restrict__ pool,
                                                   int N, int chunk) {
    int tid = threadIdx.x;
    int lane = tid & 63;
    int half_id = lane >> 5, p = lane & 31;
    int w = __builtin_amdgcn_readfirstlane(blockIdx.x * 4 + (tid >> 6));
    int start = w * chunk;
    if (start >= N) return;
    int endn = min(N, start + chunk);
    float2 b3p = *(const float2*)(b3 + 2 * p);
    int gcur = batch[start];
    float2 pacc = make_float2(0.f, 0.f);
    for (int node = start; node < endn; ++node) {
        int s = rowptr[node], e = rowptr[node + 1];
        float2 acc = gather_sum_h2(srcidx, Hs, s, e, half_id, p);
        float dc = dinv[node];
        float2 self = __half22float2(*(const __half2*)(Hs + (long)node * DD + 2 * p));
        float vx = (acc.x + self.x) * dc + b3p.x;
        float vy = (acc.y + self.y) * dc + b3p.y;
        int g = batch[node];
        if (g != gcur) {
            if (!half_id) {
                atomicAdd(&pool[gcur * DD + 2 * p],     pacc.x);
                atomicAdd(&pool[gcur * DD + 2 * p + 1], pacc.y);
            }
            gcur = g;
            pacc = make_float2(vx, vy);
        } else {
            pacc.x += vx; pacc.y += vy;
        }
    }
    if (!half_id) {
        atomicAdd(&pool[gcur * DD + 2 * p],     pacc.x);
        atomicAdd(&pool[gcur * DD + 2 * p + 1], pacc.y);
    }
}

// ---- final: mean + L2 normalize ----
__global__ void k_final(const float* __restrict__ pool, const int* __restrict__ batch,
                        float* __restrict__ out, int N) {
    int g = blockIdx.x, j = threadIdx.x;
    int lo = 0, hi = N;
    while (lo < hi) { int m = (lo + hi) >> 1; if (batch[m] < g) lo = m + 1; else hi = m; }
    int lo2 = lo; hi = N;
    while (lo2 < hi) { int m = (lo2 + hi) >> 1; if (batch[m] < g + 1) lo2 = m + 1; else hi = m; }
    float cnt = fmaxf((float)(lo2 - lo), 1.0f);
    float v = pool[g * DD + j] / cnt;
    float sq = v * v;
    #pragma unroll
    for (int off = 32; off > 0; off >>= 1) sq += __shfl_down(sq, off, 64);
    float nrm = __shfl(sq, 0, 64);
    out[g * DD + j] = v / sqrtf(nrm);
}

extern "C" void kernel_launch(void* const* d_in, const int* in_sizes, int n_in,
                              void* d_out, int out_size, void* d_ws, size_t ws_size,
                              hipStream_t stream) {
    const int*   node_types = (const int*)d_in[0];
    const int*   edge_index = (const int*)d_in[1];
    const int*   batch      = (const int*)d_in[2];
    const float* emb        = (const float*)d_in[3];
    const float* W1 = (const float*)d_in[4];
    const float* b1 = (const float*)d_in[5];
    const float* W2 = (const float*)d_in[6];
    const float* b2 = (const float*)d_in[7];
    const float* W3 = (const float*)d_in[8];
    const float* b3 = (const float*)d_in[9];
    const int N = in_sizes[0];
    const int E = in_sizes[1] / 2;
    const int V = in_sizes[3] / DD;
    const int* row = edge_index;
    const int* col = edge_index + E;
    const long ND = (long)N * DD;
    const int NB = (N + BINW - 1) / BINW;       // 391 bins
    const int CE = (E + EB - 1) / EB;           // edges per edge-block

    // workspace layout
    char* p = (char*)d_ws;
    __half*   hsA     = (__half*)p;       p += ND * sizeof(__half);
    __half*   hsB     = (__half*)p;       p += ND * sizeof(__half);
    int*      srcidx  = (int*)p;          p += (size_t)E * sizeof(int);
    unsigned* epku    = (unsigned*)p;     p += (size_t)E * sizeof(unsigned);
    unsigned* binned  = (unsigned*)p;     p += (size_t)E * sizeof(unsigned);
    int*      H       = (int*)p;          p += (size_t)EB * NB * sizeof(int);
    int*      bintot  = (int*)p;          p += (size_t)(NB + 4) * sizeof(int);
    int*      binstart= (int*)p;          p += (size_t)(NB + 4) * sizeof(int);
    float*    dinv    = (float*)p;        p += (size_t)N * sizeof(float);
    int2*     pk      = (int2*)p;         p += (size_t)N * sizeof(int2);
    int*      rowptr  = (int*)p;          p += (size_t)(N + 4) * sizeof(int);
    float*    pool    = (float*)p;        p += (size_t)NUM_GRAPHS * DD * sizeof(float);
    float*    embW1   = (float*)p;        p += (size_t)V * DD * sizeof(float);

    // ---- atomic-free sort-based CSR build ----
    k_hist<<<EB, 256, 0, stream>>>(col, H, E, NB, CE);
    k_scanA<<<NB, 256, 0, stream>>>(H, bintot, NB);
    k_scanB<<<1, 512, 0, stream>>>(bintot, binstart, NB);
    k_scatbin<<<EB, 256, 0, stream>>>(row, col, H, binstart, binned, E, NB, CE);
    k_bincsr<<<NB, 256, 0, stream>>>(binned, binstart, node_types, srcidx, rowptr,
                                     dinv, pk, N, NB);
    k_buildepk<<<(E + 255) / 256, 256, 0, stream>>>(srcidx, pk, epku, E);

    // ---- layer 1 fused with @W2*dinv -> fp16 ----
    k_embW1<<<V, DD, 0, stream>>>(emb, W1, embW1, V);
    k_agg1_fused<<<AGG_BLOCKS, 256, 0, stream>>>(rowptr, epku, pk, embW1, b1, W2,
                                                 hsA, N, V);
    // ---- layer 2 fused with @W3*dinv -> fp16 ----
    k_agg2_fused<<<AGG_BLOCKS, 256, 0, stream>>>(rowptr, srcidx, dinv, hsA, b2, W3,
                                                 hsB, N);
    // ---- layer 3 fused with pooling ----
    hipMemsetAsync(pool, 0, (size_t)(NUM_GRAPHS * DD) * sizeof(float), stream);
    const int totalWaves = AGG_BLOCKS * 4;
    const int chunk = (N + totalWaves - 1) / totalWaves;
    k_agg3_pool<<<AGG_BLOCKS, 256, 0, stream>>>(rowptr, srcidx, dinv, hsB, b3, batch,
                                                pool, N, chunk);
    // ---- normalize ----
    k_final<<<NUM_GRAPHS, DD, 0, stream>>>(pool, batch, (float*)d_out, N);
}